// Round 1
// baseline (53.701 us; speedup 1.0000x reference)
//
#include <hip/hip_runtime.h>
#include <stdint.h>

// CorrelationLayer: out[b, i*41+j, y, x] = sum_c f1[b,c,y,x]*f2[b,c,y+i-20,x+j-20]
// Formulated as banded row-pair GEMM in bf16 MFMA (32x32x16), write-bound op.
// WG = (b, y, dy-half): stage f1 row once + f2 row per dy into swizzled LDS,
// 4 waves compute the 4 32x32 tiles of C[x'][x], band-extract diag dx=-20..20.

#define NB 4
#define NC 128
#define NH 64
#define NW 64
#define PAD 20
#define ND 41
#define HW (NH * NW)

typedef __attribute__((ext_vector_type(8))) __bf16 bf16x8;
typedef __attribute__((ext_vector_type(16))) float f32x16;

__device__ __forceinline__ unsigned int f2bf(float f) {
  // fp32 -> bf16 round-to-nearest-even, result in low 16 bits
  unsigned int u = __builtin_bit_cast(unsigned int, f);
  u += 0x7FFFu + ((u >> 16) & 1u);
  return u >> 16;
}

__device__ __forceinline__ float f4elem(const float4 v, int j) {
  return j == 0 ? v.x : j == 1 ? v.y : j == 2 ? v.z : v.w;
}

// Stage one spatial row (all 128 channels, 64 x) fp32 -> bf16 into LDS,
// layout [x][c] (c contiguous, 8 bf16 = 16B units), XOR-swizzled:
// 16B-slot = x*16 + ((c>>3) ^ (x&7))  -> conflict-free ds_read_b128 fragments.
__device__ __forceinline__ void stage_row(const float* __restrict__ row,
                                          uint4* __restrict__ lds, int t) {
  const int xq = t & 15;  // x = 4*xq .. 4*xq+3
  const int cg = t >> 4;  // channels cg*8 .. cg*8+7
  const float* p = row + (size_t)cg * 8 * HW + xq * 4;
  float4 v[8];
#pragma unroll
  for (int i = 0; i < 8; ++i)
    v[i] = *(const float4*)(p + (size_t)i * HW);
#pragma unroll
  for (int j = 0; j < 4; ++j) {
    const int x = xq * 4 + j;
    uint4 u;
    u.x = f2bf(f4elem(v[0], j)) | (f2bf(f4elem(v[1], j)) << 16);
    u.y = f2bf(f4elem(v[2], j)) | (f2bf(f4elem(v[3], j)) << 16);
    u.z = f2bf(f4elem(v[4], j)) | (f2bf(f4elem(v[5], j)) << 16);
    u.w = f2bf(f4elem(v[6], j)) | (f2bf(f4elem(v[7], j)) << 16);
    lds[x * 16 + (cg ^ (x & 7))] = u;
  }
}

__global__ __launch_bounds__(256, 2) void corr_kernel(
    const float* __restrict__ feat1, const float* __restrict__ feat2,
    float* __restrict__ out) {
  __shared__ uint4 f1s[64 * 16];   // 16 KB bf16 [x][c] swizzled (B operand)
  __shared__ uint4 f2s[64 * 16];   // 16 KB bf16 [x'][c] swizzled (A operand)
  __shared__ float cbuf[64 * 64];  // 16 KB C[x'][x]

  // XCD-aware swizzle: 512 blocks % 8 == 0 -> bijective; contiguous y-band
  // per XCD so streamed f2 rows (41x reuse) stay L2-resident (~3.3 MB < 4 MB).
  const int bid = blockIdx.x;
  const int lid = (bid & 7) * 64 + (bid >> 3);
  const int half = lid & 1;
  const int y = (lid >> 1) & 63;
  const int b = lid >> 7;

  const int t = threadIdx.x;
  const int lane = t & 63;
  const int wv = t >> 6;  // wave 0..3 -> 32x32 tile (I,J)
  const int I = wv & 1;
  const int J = wv >> 1;

  // MFMA fragment addressing (mfma_f32_32x32x16_bf16):
  // A: row = lane&31 (+32I), k = 8*(lane>>5)+e ; B: col = lane&31 (+32J), same k
  const int xa = I * 32 + (lane & 31);  // x' (M dim, from f2)
  const int xb = J * 32 + (lane & 31);  // x  (N dim, from f1)
  const int kh = lane >> 5;
  const int aBase = xa * 16, aSw = xa & 7;
  const int bBase = xb * 16, bSw = xb & 7;
  // C/D layout (verified): col = lane&31, row = (r&3) + 8*(r>>2) + 4*(lane>>5)
  const int col = (lane & 31) + J * 32;
  const int rbase = kh * 4 + I * 32;

  // band-extract / store mapping
  const int xg = t & 63;
  const int g = t >> 6;

  const float* f1row = feat1 + (size_t)b * NC * HW + (size_t)y * NW;
  const float* f2base = feat2 + (size_t)b * NC * HW;

  stage_row(f1row, f1s, t);  // visible after first __syncthreads below

  const int dy0 = half * 21;
  const int dy1 = half ? ND : 21;
  const size_t outBase = ((size_t)b * (ND * ND) * NH + y) * NW;

  for (int di = dy0; di < dy1; ++di) {
    const int yp = y + di - PAD;
    const size_t dBase = outBase + (size_t)di * ND * HW;
    if (yp < 0 || yp >= NH) {  // block-uniform: whole d-row is zero padding
      for (int k = g; k < ND; k += 4)
        out[dBase + (size_t)k * HW + xg] = 0.f;
      continue;
    }
    stage_row(f2base + (size_t)yp * NW, f2s, t);
    __syncthreads();  // f1s/f2s ready; prev extract done (cbuf safe to write)

    f32x16 acc;
#pragma unroll
    for (int r = 0; r < 16; ++r) acc[r] = 0.f;
#pragma unroll
    for (int ks = 0; ks < 8; ++ks) {
      const int q = ks * 2 + kh;  // 8-channel group index
      bf16x8 a = __builtin_bit_cast(bf16x8, f2s[aBase + (q ^ aSw)]);
      bf16x8 bb = __builtin_bit_cast(bf16x8, f1s[bBase + (q ^ bSw)]);
      acc = __builtin_amdgcn_mfma_f32_32x32x16_bf16(a, bb, acc, 0, 0, 0);
    }
#pragma unroll
    for (int r = 0; r < 16; ++r) {
      const int row = rbase + (r & 3) + 8 * (r >> 2);
      cbuf[row * 64 + col] = acc[r];  // bank = col%32: conflict-free
    }
    __syncthreads();  // cbuf ready

    // diagonal extract: out[b, di*41+k, y, x] = C[x+k-20][x]
    for (int k = g; k < ND; k += 4) {
      const int xs = xg + k - PAD;
      const float vv = (xs >= 0 && xs < NW) ? cbuf[xs * 64 + xg] : 0.f;
      out[dBase + (size_t)k * HW + xg] = vv;  // 64-lane coalesced row
    }
  }
}

extern "C" void kernel_launch(void* const* d_in, const int* in_sizes, int n_in,
                              void* d_out, int out_size, void* d_ws,
                              size_t ws_size, hipStream_t stream) {
  (void)in_sizes; (void)n_in; (void)out_size; (void)d_ws; (void)ws_size;
  const float* f1 = (const float*)d_in[0];
  const float* f2 = (const float*)d_in[1];
  float* out = (float*)d_out;
  corr_kernel<<<dim3(NB * NH * 2), dim3(256), 0, stream>>>(f1, f2, out);
}

// Round 2
// 48.503 us; speedup vs baseline: 1.1072x; 1.1072x over previous
//
#include <hip/hip_runtime.h>
#include <stdint.h>

// CorrelationLayer: out[b, i*41+j, y, x] = sum_c f1[b,c,y,x]*f2[b,c,y+i-20,x+j-20]
// Banded row-pair GEMM in bf16 MFMA (32x32x16). WG = (b, y, dy-half).
// R2: register-prefetch pipeline (issue next f2 row's loads before computing
// current -> load latency hides under MFMA+extract), 3 blocks/CU, boundary
// zero-fills hoisted out of the steady-state loop. Single f2 LDS buffer is
// race-free: writes sit between barrier2(i-1) and barrier1(i); reads between
// barrier1(i) and barrier2(i).

#define NB 4
#define NC 128
#define NH 64
#define NW 64
#define PAD 20
#define ND 41
#define HW (NH * NW)

typedef __attribute__((ext_vector_type(8))) __bf16 bf16x8;
typedef __attribute__((ext_vector_type(16))) float f32x16;

__device__ __forceinline__ unsigned int f2bf(float f) {
  // fp32 -> bf16 round-to-nearest-even, result in low 16 bits
  unsigned int u = __builtin_bit_cast(unsigned int, f);
  u += 0x7FFFu + ((u >> 16) & 1u);
  return u >> 16;
}

__device__ __forceinline__ float f4elem(const float4 v, int j) {
  return j == 0 ? v.x : j == 1 ? v.y : j == 2 ? v.z : v.w;
}

// Convert 8x float4 (thread's 32 staged elems) -> bf16 LDS [x][c] layout,
// XOR-swizzled: 16B-slot = x*16 + ((c>>3) ^ (x&7)), conflict-free b128 reads.
__device__ __forceinline__ void convwrite(const float4 (&v)[8],
                                          uint4* __restrict__ lds, int xq,
                                          int cg) {
#pragma unroll
  for (int j = 0; j < 4; ++j) {
    const int x = xq * 4 + j;
    uint4 u;
    u.x = f2bf(f4elem(v[0], j)) | (f2bf(f4elem(v[1], j)) << 16);
    u.y = f2bf(f4elem(v[2], j)) | (f2bf(f4elem(v[3], j)) << 16);
    u.z = f2bf(f4elem(v[4], j)) | (f2bf(f4elem(v[5], j)) << 16);
    u.w = f2bf(f4elem(v[6], j)) | (f2bf(f4elem(v[7], j)) << 16);
    lds[x * 16 + (cg ^ (x & 7))] = u;
  }
}

__global__ __launch_bounds__(256, 3) void corr_kernel(
    const float* __restrict__ feat1, const float* __restrict__ feat2,
    float* __restrict__ out) {
  __shared__ uint4 f1s[64 * 16];   // 16 KB bf16 [x][c] swizzled (B operand)
  __shared__ uint4 f2s[64 * 16];   // 16 KB bf16 [x'][c] swizzled (A operand)
  __shared__ float cbuf[64 * 64];  // 16 KB C[x'][x]

  // XCD-aware swizzle: 512 blocks % 8 == 0 bijective; contiguous y-band per
  // XCD keeps the 41x-reused f2 rows L2-resident (~2.3 MB < 4 MB/XCD).
  const int bid = blockIdx.x;
  const int lid = (bid & 7) * 64 + (bid >> 3);
  const int half = lid & 1;
  const int y = (lid >> 1) & 63;
  const int b = lid >> 7;

  const int t = threadIdx.x;
  const int lane = t & 63;
  const int wv = t >> 6;  // wave 0..3 -> 32x32 tile (I,J)
  const int I = wv & 1;
  const int J = wv >> 1;

  // mfma_f32_32x32x16_bf16 fragments: A row = lane&31 (+32I), B col = lane&31
  // (+32J), k-half = lane>>5. C/D: col=lane&31, row=(r&3)+8*(r>>2)+4*(lane>>5)
  const int xa = I * 32 + (lane & 31);  // x' (M, from f2)
  const int xb = J * 32 + (lane & 31);  // x  (N, from f1)
  const int kh = lane >> 5;
  const int aBase = xa * 16, aSw = xa & 7;
  const int bBase = xb * 16, bSw = xb & 7;
  const int col = (lane & 31) + J * 32;
  const int rbase = kh * 4 + I * 32;

  const int xg = t & 63;  // extract/store mapping
  const int g = t >> 6;

  // staging mapping: thread covers x = 4*xq..4*xq+3, channels 8*cg..8*cg+7
  const int xq = t & 15;
  const int cg = t >> 4;
  const size_t rowoff = (size_t)cg * 8 * HW + xq * 4;
  const float* f1row = feat1 + (size_t)b * NC * HW + (size_t)y * NW + rowoff;
  const float* f2row0 = feat2 + (size_t)b * NC * HW + rowoff;

  const size_t outBase = ((size_t)b * (ND * ND) * NH + y) * NW;

  // valid-di range is contiguous per half
  int dBeg, dEnd;
  if (half == 0) {
    dBeg = (y < PAD) ? (PAD - y) : 0;
    dEnd = PAD + 1;
  } else {
    dBeg = PAD + 1;
    const int e = (NH + PAD) - y;  // di < 84-y
    dEnd = e < ND ? e : ND;
  }

  // boundary zero-fill (no staging, no barriers)
  const int zBeg = half ? dEnd : 0;
  const int zEnd = half ? ND : dBeg;
  for (int di = zBeg; di < zEnd; ++di) {
    const size_t dB = outBase + (size_t)di * ND * HW;
    for (int k = g; k < ND; k += 4) out[dB + (size_t)k * HW + xg] = 0.f;
  }
  if (dBeg >= dEnd) return;  // block-uniform (half==1, y==63)

  float4 v[8];
  // stage f1 row (once)
#pragma unroll
  for (int i = 0; i < 8; ++i) v[i] = *(const float4*)(f1row + (size_t)i * HW);
  convwrite(v, f1s, xq, cg);
  // issue first f2 row loads
  {
    const int yp = y + dBeg - PAD;
#pragma unroll
    for (int i = 0; i < 8; ++i)
      v[i] = *(const float4*)(f2row0 + (size_t)yp * NW + (size_t)i * HW);
  }

#pragma unroll 1
  for (int di = dBeg; di < dEnd; ++di) {
    convwrite(v, f2s, xq, cg);  // waits on current loads, writes LDS
    // prefetch NEXT f2 row into regs: latency hides under mfma+extract
    {
      const int nx = (di + 1 < dEnd) ? di + 1 : di;
      const int ypn = y + nx - PAD;
#pragma unroll
      for (int i = 0; i < 8; ++i)
        v[i] = *(const float4*)(f2row0 + (size_t)ypn * NW + (size_t)i * HW);
    }
    __syncthreads();  // f1s/f2s ready (also: prev extract done -> cbuf free)

    f32x16 acc;
#pragma unroll
    for (int r = 0; r < 16; ++r) acc[r] = 0.f;
#pragma unroll
    for (int ks = 0; ks < 8; ++ks) {
      const int q = ks * 2 + kh;
      bf16x8 a = __builtin_bit_cast(bf16x8, f2s[aBase + (q ^ aSw)]);
      bf16x8 bb = __builtin_bit_cast(bf16x8, f1s[bBase + (q ^ bSw)]);
      acc = __builtin_amdgcn_mfma_f32_32x32x16_bf16(a, bb, acc, 0, 0, 0);
    }
#pragma unroll
    for (int r = 0; r < 16; ++r) {
      const int row = rbase + (r & 3) + 8 * (r >> 2);
      cbuf[row * 64 + col] = acc[r];  // bank = col%32: 2-way = free
    }
    __syncthreads();  // cbuf ready

    // diagonal extract: out[b, di*41+k, y, x] = C[x+k-20][x]
    const size_t dBase = outBase + (size_t)di * ND * HW;
    for (int k = g; k < ND; k += 4) {
      const int xs = xg + k - PAD;
      const float vv = (xs >= 0 && xs < NW) ? cbuf[xs * 64 + xg] : 0.f;
      out[dBase + (size_t)k * HW + xg] = vv;  // 64-lane coalesced row
    }
  }
}

extern "C" void kernel_launch(void* const* d_in, const int* in_sizes, int n_in,
                              void* d_out, int out_size, void* d_ws,
                              size_t ws_size, hipStream_t stream) {
  (void)in_sizes; (void)n_in; (void)out_size; (void)d_ws; (void)ws_size;
  const float* f1 = (const float*)d_in[0];
  const float* f2 = (const float*)d_in[1];
  float* out = (float*)d_out;
  corr_kernel<<<dim3(NB * NH * 2), dim3(256), 0, stream>>>(f1, f2, out);
}

// Round 3
// 42.248 us; speedup vs baseline: 1.2711x; 1.1481x over previous
//
#include <hip/hip_runtime.h>
#include <stdint.h>

// CorrelationLayer: out[b, i*41+j, y, x] = sum_c f1[b,c,y,x]*f2[b,c,y+i-20,x+j-20]
// Banded row-pair GEMM in bf16 MFMA (32x32x16). WG = (b, y, dy-half).
// R3: ONE barrier/iter (dbuf f2s + dbuf cbuf, extract lags one iter),
// f1 B-fragment hoisted to registers (loop-invariant), fp32->bf16 via
// compiler casts (v_cvt_pk_bf16_f32), nontemporal output stores.

#define NB 4
#define NC 128
#define NH 64
#define NW 64
#define PAD 20
#define ND 41
#define HW (NH * NW)

typedef __attribute__((ext_vector_type(8))) __bf16 bf16x8;
typedef __attribute__((ext_vector_type(16))) float f32x16;

__device__ __forceinline__ float f4elem(const float4 v, int j) {
  return j == 0 ? v.x : j == 1 ? v.y : j == 2 ? v.z : v.w;
}

__device__ __forceinline__ unsigned int pk2(float a, float b) {
  // compiler folds to v_cvt_pk_bf16_f32 (RNE)
  unsigned short lo = __builtin_bit_cast(unsigned short, (__bf16)a);
  unsigned short hi = __builtin_bit_cast(unsigned short, (__bf16)b);
  return (unsigned int)lo | ((unsigned int)hi << 16);
}

// Convert thread's 32 staged fp32 -> bf16 LDS [x][c], XOR-swizzled:
// 16B-slot = x*16 + ((c>>3) ^ (x&7)) -> conflict-free ds_read_b128 fragments.
__device__ __forceinline__ void convwrite(const float4 (&v)[8],
                                          uint4* __restrict__ lds, int xq,
                                          int cg) {
#pragma unroll
  for (int j = 0; j < 4; ++j) {
    const int x = xq * 4 + j;
    uint4 u;
    u.x = pk2(f4elem(v[0], j), f4elem(v[1], j));
    u.y = pk2(f4elem(v[2], j), f4elem(v[3], j));
    u.z = pk2(f4elem(v[4], j), f4elem(v[5], j));
    u.w = pk2(f4elem(v[6], j), f4elem(v[7], j));
    lds[x * 16 + (cg ^ (x & 7))] = u;
  }
}

__global__ __launch_bounds__(256, 2) void corr_kernel(
    const float* __restrict__ feat1, const float* __restrict__ feat2,
    float* __restrict__ out) {
  __shared__ uint4 f2s[2][64 * 16];   // 32 KB bf16 [x'][c] swizzled (A), dbuf
  __shared__ float cbuf[2][64 * 64];  // 32 KB C[x'][x], dbuf; cbuf[0] aliased
                                      // as f1 staging scratch in prologue

  // XCD-aware swizzle: 512 blocks, bijective; contiguous y-band per XCD keeps
  // the 41x-reused f2 rows L2-resident (~2.3 MB < 4 MB/XCD).
  const int bid = blockIdx.x;
  const int lid = (bid & 7) * 64 + (bid >> 3);
  const int half = lid & 1;
  const int y = (lid >> 1) & 63;
  const int b = lid >> 7;

  const int t = threadIdx.x;
  const int lane = t & 63;
  const int wv = t >> 6;  // wave -> 32x32 tile (I,J)
  const int I = wv & 1;
  const int J = wv >> 1;

  // mfma_f32_32x32x16_bf16: A row = lane&31 (+32I), B col = lane&31 (+32J),
  // k-half = lane>>5. C/D: col = lane&31, row = (r&3)+8*(r>>2)+4*(lane>>5).
  const int xa = I * 32 + (lane & 31);  // x' (M, from f2)
  const int xb = J * 32 + (lane & 31);  // x  (N, from f1)
  const int kh = lane >> 5;
  const int aBase = xa * 16, aSw = xa & 7;
  const int bBase = xb * 16, bSw = xb & 7;
  const int col = (lane & 31) + J * 32;
  const int rbase = kh * 4 + I * 32;

  const int xg = t & 63;  // extract/store mapping
  const int g = t >> 6;

  // staging: thread covers x = 4*xq..4*xq+3, channels 8*cg..8*cg+7
  const int xq = t & 15;
  const int cg = t >> 4;
  const size_t rowoff = (size_t)cg * 8 * HW + xq * 4;
  const float* f1row = feat1 + (size_t)b * NC * HW + (size_t)y * NW + rowoff;
  const float* f2row0 = feat2 + (size_t)b * NC * HW + rowoff;
  const size_t outBase = ((size_t)b * (ND * ND) * NH + y) * NW;

  // valid-di range is contiguous per half
  int dBeg, dEnd;
  if (half == 0) {
    dBeg = (y < PAD) ? (PAD - y) : 0;
    dEnd = PAD + 1;
  } else {
    dBeg = PAD + 1;
    const int e = (NH + PAD) - y;
    dEnd = e < ND ? e : ND;
  }

  // boundary zero-fill (no barriers involved)
  const int zBeg = half ? dEnd : 0;
  const int zEnd = half ? ND : dBeg;
  for (int di = zBeg; di < zEnd; ++di) {
    const size_t dB = outBase + (size_t)di * ND * HW;
    for (int k = g; k < ND; k += 4)
      __builtin_nontemporal_store(0.f, &out[dB + (size_t)k * HW + xg]);
  }
  if (dBeg >= dEnd) return;  // block-uniform (half==1, y==63)

  float4 v[8];
  // stage f1 row into cbuf[0]-aliased scratch
#pragma unroll
  for (int i = 0; i < 8; ++i) v[i] = *(const float4*)(f1row + (size_t)i * HW);
  uint4* f1tmp = (uint4*)&cbuf[0][0];
  convwrite(v, f1tmp, xq, cg);
  // issue first f2 row loads (latency overlaps barrier + bfrag reads)
  {
    const int yp0 = y + dBeg - PAD;
#pragma unroll
    for (int i = 0; i < 8; ++i)
      v[i] = *(const float4*)(f2row0 + (size_t)yp0 * NW + (size_t)i * HW);
  }
  __syncthreads();  // f1 staging visible
  bf16x8 bfrag[8];  // loop-invariant B operand in registers
#pragma unroll
  for (int ks = 0; ks < 8; ++ks) {
    const int q = ks * 2 + kh;
    bfrag[ks] = __builtin_bit_cast(bf16x8, f1tmp[bBase + (q ^ bSw)]);
  }
  __syncthreads();  // bfrag reads drained (lgkmcnt(0) pre-barrier) ->
                    // cbuf[0] free for MFMA writes

  const int nIter = dEnd - dBeg;
  int p = 0;
#pragma unroll 1
  for (int j = 0; j < nIter; ++j) {
    convwrite(v, f2s[p], xq, cg);  // waits only on its loads (vmcnt-counted)
    // prefetch next f2 row; latency hides under MFMA+extract+stores
    {
      const int nj = (j + 1 < nIter) ? j + 1 : j;
      const int ypn = y + dBeg + nj - PAD;
#pragma unroll
      for (int i = 0; i < 8; ++i)
        v[i] = *(const float4*)(f2row0 + (size_t)ypn * NW + (size_t)i * HW);
    }
    __syncthreads();  // the ONLY barrier: f2s[p] ready; cbuf(j-1) visible

    f32x16 acc;
#pragma unroll
    for (int r = 0; r < 16; ++r) acc[r] = 0.f;
#pragma unroll
    for (int ks = 0; ks < 8; ++ks) {
      const int q = ks * 2 + kh;
      bf16x8 a = __builtin_bit_cast(bf16x8, f2s[p][aBase + (q ^ aSw)]);
      acc = __builtin_amdgcn_mfma_f32_32x32x16_bf16(a, bfrag[ks], acc, 0, 0, 0);
    }
#pragma unroll
    for (int r = 0; r < 16; ++r) {
      const int row = rbase + (r & 3) + 8 * (r >> 2);
      cbuf[p][row * 64 + col] = acc[r];  // bank = col%32: 2-way = free
    }

    if (j > 0) {  // extract PREVIOUS iteration's C (barrier-separated)
      const size_t dBase = outBase + (size_t)(dBeg + j - 1) * ND * HW;
      const float* cb = cbuf[p ^ 1];
      for (int k = g; k < ND; k += 4) {
        const int xs = xg + k - PAD;
        const float vv = (xs >= 0 && xs < NW) ? cb[xs * 64 + xg] : 0.f;
        __builtin_nontemporal_store(vv, &out[dBase + (size_t)k * HW + xg]);
      }
    }
    p ^= 1;
  }

  __syncthreads();  // last cbuf visible
  {
    const size_t dBase = outBase + (size_t)(dEnd - 1) * ND * HW;
    const float* cb = cbuf[p ^ 1];
    for (int k = g; k < ND; k += 4) {
      const int xs = xg + k - PAD;
      const float vv = (xs >= 0 && xs < NW) ? cb[xs * 64 + xg] : 0.f;
      __builtin_nontemporal_store(vv, &out[dBase + (size_t)k * HW + xg]);
    }
  }
}

extern "C" void kernel_launch(void* const* d_in, const int* in_sizes, int n_in,
                              void* d_out, int out_size, void* d_ws,
                              size_t ws_size, hipStream_t stream) {
  (void)in_sizes; (void)n_in; (void)out_size; (void)d_ws; (void)ws_size;
  const float* f1 = (const float*)d_in[0];
  const float* f2 = (const float*)d_in[1];
  float* out = (float*)d_out;
  corr_kernel<<<dim3(NB * NH * 2), dim3(256), 0, stream>>>(f1, f2, out);
}

// Round 4
// 38.125 us; speedup vs baseline: 1.4085x; 1.1081x over previous
//
#include <hip/hip_runtime.h>
#include <stdint.h>

// CorrelationLayer: out[b, i*41+j, y, x] = sum_c f1[b,c,y,x]*f2[b,c,y+i-20,x+j-20]
// R4: two-kernel plan.
//  (1) conv_kernel: fp32 -> bf16 once, layout f_t[b][y][q=c/8][x] (uint4 = 8
//      channels at one (y,x)) in d_ws. Kills per-iteration cvt + LDS staging.
//  (2) corr_main: block = (b, y, dy-quarter), 1024 blocks = 4/CU. Per-lane A
//      fragments loaded straight from f2t (8x dwordx4, two 512B segments per
//      wave, L2-resident 41x reuse); f1 B-fragments in registers; LDS only a
//      32KB double-buffered C tile; ONE barrier/iter with lag-extract.
// Fallback to the single-kernel R3 path if ws_size < 8MB.

#define NB 4
#define NC 128
#define NH 64
#define NW 64
#define PAD 20
#define ND 41
#define HW (NH * NW)
#define ROW_U4 1024  // 16 q-groups * 64 x per (b,y) row, in uint4 units

typedef __attribute__((ext_vector_type(8))) __bf16 bf16x8;
typedef __attribute__((ext_vector_type(16))) float f32x16;

__device__ __forceinline__ unsigned int pk2(float a, float b) {
  // folds to v_cvt_pk_bf16_f32 (RNE)
  unsigned short lo = __builtin_bit_cast(unsigned short, (__bf16)a);
  unsigned short hi = __builtin_bit_cast(unsigned short, (__bf16)b);
  return (unsigned int)lo | ((unsigned int)hi << 16);
}

// ---------------- kernel 1: fp32 -> bf16 repack --------------------------
// f_t[((b*64+y)*16 + q)*64 + x] (uint4) = channels 8q..8q+7 at (y,x), bf16.
__global__ __launch_bounds__(256) void conv_kernel(
    const float* __restrict__ f1, const float* __restrict__ f2,
    uint4* __restrict__ ws) {
  const int blk = blockIdx.x;  // 0..511
  const int isF2 = blk >> 8;
  const int by = blk & 255;  // b*64+y
  const int b = by >> 6, y = by & 63;
  const float* src = (isF2 ? f2 : f1) + (size_t)b * NC * HW + (size_t)y * NW;
  uint4* dst = ws + (size_t)isF2 * (NB * NH * ROW_U4) + (size_t)by * ROW_U4;
  const int x = threadIdx.x & 63;   // loads: 64 lanes consecutive x = 256B
  const int cq = threadIdx.x >> 6;  // 0..3
#pragma unroll
  for (int it = 0; it < 4; ++it) {
    const int cg = it * 4 + cq;
    float v[8];
#pragma unroll
    for (int i = 0; i < 8; ++i) v[i] = src[(size_t)(cg * 8 + i) * HW + x];
    uint4 u;
    u.x = pk2(v[0], v[1]);
    u.y = pk2(v[2], v[3]);
    u.z = pk2(v[4], v[5]);
    u.w = pk2(v[6], v[7]);
    dst[cg * 64 + x] = u;  // 64 lanes consecutive x: 1KB contiguous store
  }
}

// ---------------- kernel 2: banded MFMA correlation -----------------------
__global__ __launch_bounds__(256, 4) void corr_main(
    const uint4* __restrict__ ws, float* __restrict__ out) {
  __shared__ float cbuf[2][64 * 64];  // 32 KB total -> 4 blocks/CU

  // XCD swizzle: 1024 blocks, 128/XCD chunk; dq fastest then y -> each XCD
  // touches a 32-wide y band: f2t working set ~1.2MB, L2-resident.
  const int bid = blockIdx.x;
  const int lid = (bid & 7) * 128 + (bid >> 3);
  const int dq = lid & 3;
  const int y = (lid >> 2) & 63;
  const int b = lid >> 8;

  const int t = threadIdx.x;
  const int lane = t & 63;
  const int wv = t >> 6;  // wave -> 32x32 C tile (I=row half, J=col half)
  const int I = wv & 1;
  const int J = wv >> 1;
  const int kh = lane >> 5;

  // mfma_f32_32x32x16_bf16: A row = lane&31 (+32I), B col = lane&31 (+32J),
  // frag ks = channels 16ks+8kh..+8 -> q = 2ks+kh.
  // C/D: col = lane&31 (+32J), row = 32I + 4kh + (r&3) + 8*(r>>2).
  const int xa = I * 32 + (lane & 31);
  const int xb = J * 32 + (lane & 31);
  const int col = (lane & 31) + 32 * J;
  const int rbase = kh * 4 + I * 32;
  const int xg = t & 63;  // extract/store mapping
  const int g = t >> 6;

  const uint4* f1t = ws;
  const uint4* f2t = ws + NB * NH * ROW_U4;

  const int dBeg = (ND * dq) / 4;        // 0,10,20,30
  const int dEnd = (ND * (dq + 1)) / 4;  // 10,20,30,41
  // valid di: 0 <= y+di-20 < 64  ->  di in [20-y, 84-y)
  int a0 = 20 - y;
  if (a0 < dBeg) a0 = dBeg;
  if (a0 > dEnd) a0 = dEnd;
  int a1 = 84 - y;
  if (a1 < a0) a1 = a0;
  if (a1 > dEnd) a1 = dEnd;

  const size_t outBase = (size_t)b * (ND * ND) * HW + (size_t)y * NW;

  // zero planes: [dBeg,a0) and [a1,dEnd)
  for (int di = dBeg; di < a0; ++di) {
    const size_t dB = outBase + (size_t)di * ND * HW;
    for (int k = g; k < ND; k += 4)
      __builtin_nontemporal_store(0.f, &out[dB + (size_t)k * HW + xg]);
  }
  for (int di = a1; di < dEnd; ++di) {
    const size_t dB = outBase + (size_t)di * ND * HW;
    for (int k = g; k < ND; k += 4)
      __builtin_nontemporal_store(0.f, &out[dB + (size_t)k * HW + xg]);
  }
  const int n = a1 - a0;
  if (n <= 0) return;

  // loop-invariant B fragments (f1 row y), 8x dwordx4
  const uint4* f1row = f1t + (size_t)(b * 64 + y) * ROW_U4 + kh * 64 + xb;
  bf16x8 bfrag[8];
#pragma unroll
  for (int ks = 0; ks < 8; ++ks)
    bfrag[ks] = __builtin_bit_cast(bf16x8, f1row[ks * 128]);

  const uint4* f2row = f2t + (size_t)(b * 64) * ROW_U4 + kh * 64 + xa;

  int p = 0;
#pragma unroll 1
  for (int j = 0; j < n; ++j) {
    const int yp = y + (a0 + j) - PAD;
    const uint4* ap = f2row + (size_t)yp * ROW_U4;
    uint4 a[8];  // A fragments for this di, issued first
#pragma unroll
    for (int ks = 0; ks < 8; ++ks) a[ks] = ap[ks * 128];

    if (j > 0) {  // lag-extract previous C while A loads are in flight
      const size_t dB = outBase + (size_t)(a0 + j - 1) * ND * HW;
      const float* cb = cbuf[p ^ 1];
      for (int k = g; k < ND; k += 4) {
        const int xs = xg + k - PAD;
        const float vv = (xs >= 0 && xs < NW) ? cb[xs * 64 + xg] : 0.f;
        __builtin_nontemporal_store(vv, &out[dB + (size_t)k * HW + xg]);
      }
    }

    f32x16 acc;
#pragma unroll
    for (int r = 0; r < 16; ++r) acc[r] = 0.f;
#pragma unroll
    for (int ks = 0; ks < 8; ++ks)
      acc = __builtin_amdgcn_mfma_f32_32x32x16_bf16(
          __builtin_bit_cast(bf16x8, a[ks]), bfrag[ks], acc, 0, 0, 0);
#pragma unroll
    for (int r = 0; r < 16; ++r) {
      const int row = rbase + (r & 3) + 8 * (r >> 2);
      cbuf[p][row * 64 + col] = acc[r];  // banks 0..31 per half-wave: free
    }
    __syncthreads();  // cbuf[p] ready; prior extract reads drained
    p ^= 1;
  }

  {  // epilogue extract
    const size_t dB = outBase + (size_t)(a0 + n - 1) * ND * HW;
    const float* cb = cbuf[p ^ 1];
    for (int k = g; k < ND; k += 4) {
      const int xs = xg + k - PAD;
      const float vv = (xs >= 0 && xs < NW) ? cb[xs * 64 + xg] : 0.f;
      __builtin_nontemporal_store(vv, &out[dB + (size_t)k * HW + xg]);
    }
  }
}

// ---------------- fallback (R3 single-kernel path) ------------------------
__device__ __forceinline__ float f4elem(const float4 v, int j) {
  return j == 0 ? v.x : j == 1 ? v.y : j == 2 ? v.z : v.w;
}

__device__ __forceinline__ void convwrite(const float4 (&v)[8],
                                          uint4* __restrict__ lds, int xq,
                                          int cg) {
#pragma unroll
  for (int j = 0; j < 4; ++j) {
    const int x = xq * 4 + j;
    uint4 u;
    u.x = pk2(f4elem(v[0], j), f4elem(v[1], j));
    u.y = pk2(f4elem(v[2], j), f4elem(v[3], j));
    u.z = pk2(f4elem(v[4], j), f4elem(v[5], j));
    u.w = pk2(f4elem(v[6], j), f4elem(v[7], j));
    lds[x * 16 + (cg ^ (x & 7))] = u;
  }
}

__global__ __launch_bounds__(256, 2) void corr_fallback(
    const float* __restrict__ feat1, const float* __restrict__ feat2,
    float* __restrict__ out) {
  __shared__ uint4 f2s[2][64 * 16];
  __shared__ float cbuf[2][64 * 64];

  const int bid = blockIdx.x;
  const int lid = (bid & 7) * 64 + (bid >> 3);
  const int half = lid & 1;
  const int y = (lid >> 1) & 63;
  const int b = lid >> 7;

  const int t = threadIdx.x;
  const int lane = t & 63;
  const int wv = t >> 6;
  const int I = wv & 1;
  const int J = wv >> 1;
  const int xa = I * 32 + (lane & 31);
  const int xb = J * 32 + (lane & 31);
  const int kh = lane >> 5;
  const int aBase = xa * 16, aSw = xa & 7;
  const int bBase = xb * 16, bSw = xb & 7;
  const int col = (lane & 31) + J * 32;
  const int rbase = kh * 4 + I * 32;
  const int xg = t & 63;
  const int g = t >> 6;
  const int xq = t & 15;
  const int cg = t >> 4;
  const size_t rowoff = (size_t)cg * 8 * HW + xq * 4;
  const float* f1row = feat1 + (size_t)b * NC * HW + (size_t)y * NW + rowoff;
  const float* f2row0 = feat2 + (size_t)b * NC * HW + rowoff;
  const size_t outBase = ((size_t)b * (ND * ND) * NH + y) * NW;

  int dBeg, dEnd;
  if (half == 0) {
    dBeg = (y < PAD) ? (PAD - y) : 0;
    dEnd = PAD + 1;
  } else {
    dBeg = PAD + 1;
    const int e = (NH + PAD) - y;
    dEnd = e < ND ? e : ND;
  }
  const int zBeg = half ? dEnd : 0;
  const int zEnd = half ? ND : dBeg;
  for (int di = zBeg; di < zEnd; ++di) {
    const size_t dB = outBase + (size_t)di * ND * HW;
    for (int k = g; k < ND; k += 4)
      __builtin_nontemporal_store(0.f, &out[dB + (size_t)k * HW + xg]);
  }
  if (dBeg >= dEnd) return;

  float4 v[8];
#pragma unroll
  for (int i = 0; i < 8; ++i) v[i] = *(const float4*)(f1row + (size_t)i * HW);
  uint4* f1tmp = (uint4*)&cbuf[0][0];
  convwrite(v, f1tmp, xq, cg);
  {
    const int yp0 = y + dBeg - PAD;
#pragma unroll
    for (int i = 0; i < 8; ++i)
      v[i] = *(const float4*)(f2row0 + (size_t)yp0 * NW + (size_t)i * HW);
  }
  __syncthreads();
  bf16x8 bfrag[8];
#pragma unroll
  for (int ks = 0; ks < 8; ++ks) {
    const int q = ks * 2 + kh;
    bfrag[ks] = __builtin_bit_cast(bf16x8, f1tmp[bBase + (q ^ bSw)]);
  }
  __syncthreads();

  const int nIter = dEnd - dBeg;
  int p = 0;
#pragma unroll 1
  for (int j = 0; j < nIter; ++j) {
    convwrite(v, f2s[p], xq, cg);
    {
      const int nj = (j + 1 < nIter) ? j + 1 : j;
      const int ypn = y + dBeg + nj - PAD;
#pragma unroll
      for (int i = 0; i < 8; ++i)
        v[i] = *(const float4*)(f2row0 + (size_t)ypn * NW + (size_t)i * HW);
    }
    __syncthreads();

    f32x16 acc;
#pragma unroll
    for (int r = 0; r < 16; ++r) acc[r] = 0.f;
#pragma unroll
    for (int ks = 0; ks < 8; ++ks) {
      const int q = ks * 2 + kh;
      bf16x8 aa = __builtin_bit_cast(bf16x8, f2s[p][aBase + (q ^ aSw)]);
      acc = __builtin_amdgcn_mfma_f32_32x32x16_bf16(aa, bfrag[ks], acc, 0, 0, 0);
    }
#pragma unroll
    for (int r = 0; r < 16; ++r) {
      const int row = rbase + (r & 3) + 8 * (r >> 2);
      cbuf[p][row * 64 + col] = acc[r];
    }
    if (j > 0) {
      const size_t dBase = outBase + (size_t)(dBeg + j - 1) * ND * HW;
      const float* cb = cbuf[p ^ 1];
      for (int k = g; k < ND; k += 4) {
        const int xs = xg + k - PAD;
        const float vv = (xs >= 0 && xs < NW) ? cb[xs * 64 + xg] : 0.f;
        __builtin_nontemporal_store(vv, &out[dBase + (size_t)k * HW + xg]);
      }
    }
    p ^= 1;
  }
  __syncthreads();
  {
    const size_t dBase = outBase + (size_t)(dEnd - 1) * ND * HW;
    const float* cb = cbuf[p ^ 1];
    for (int k = g; k < ND; k += 4) {
      const int xs = xg + k - PAD;
      const float vv = (xs >= 0 && xs < NW) ? cb[xs * 64 + xg] : 0.f;
      __builtin_nontemporal_store(vv, &out[dBase + (size_t)k * HW + xg]);
    }
  }
}

extern "C" void kernel_launch(void* const* d_in, const int* in_sizes, int n_in,
                              void* d_out, int out_size, void* d_ws,
                              size_t ws_size, hipStream_t stream) {
  (void)in_sizes; (void)n_in; (void)out_size;
  const float* f1 = (const float*)d_in[0];
  const float* f2 = (const float*)d_in[1];
  float* out = (float*)d_out;
  const size_t need = (size_t)2 * NB * NH * ROW_U4 * sizeof(uint4);  // 8 MB
  if (ws_size >= need && d_ws != nullptr) {
    uint4* ws = (uint4*)d_ws;
    conv_kernel<<<dim3(512), dim3(256), 0, stream>>>(f1, f2, ws);
    corr_main<<<dim3(NB * NH * 4), dim3(256), 0, stream>>>(ws, out);
  } else {
    corr_fallback<<<dim3(NB * NH * 2), dim3(256), 0, stream>>>(f1, f2, out);
  }
}